// Round 1
// baseline (457.222 us; speedup 1.0000x reference)
//
#include <hip/hip_runtime.h>

#define NB 8
#define LQ 4096
#define CD 256
#define NH 8
#define NL 4
#define NP 4
#define NLQ (NB*LQ)   // 32768

// Level geometry (hardcoded from SPATIAL_SHAPES = [[100,100],[50,50],[25,25],[13,13]])
// starts: 0, 10000, 12500, 13125 ; total 13294

// ---------------------------------------------------------------------------
// Kernel A: q @ [W_off | W_attn] + bias, softmax over 16 logits per head,
// sampling-location computation. 32 queries per block, 256 threads.
// ---------------------------------------------------------------------------
__global__ __launch_bounds__(256) void proj_kernel(
    const float* __restrict__ query,
    const float* __restrict__ refp,
    const float* __restrict__ W_off, const float* __restrict__ b_off,
    const float* __restrict__ W_attn, const float* __restrict__ b_attn,
    float* __restrict__ ws_loc, float* __restrict__ ws_attn)
{
    __shared__ float smem[32 * 384];   // 48 KB; first 32*256 = q tile, later res[32][384]
    const int t = threadIdx.x;
    const int base = blockIdx.x * 32;

    // load q tile (coalesced in c)
    for (int idx = t; idx < 32 * 256; idx += 256) {
        int i = idx >> 8, c = idx & 255;
        int gq = base + i;
        int n = gq >> 12, lq = gq & 4095;
        smem[idx] = query[(lq * 8 + n) * 256 + c];
    }
    __syncthreads();

    const int tq = t >> 5;   // 0..7  -> owns queries tq*4 .. tq*4+3
    const int tc = t & 31;   // 0..31 -> owns cols tc + 32*u, u in 0..11

    float acc[4][12];
#pragma unroll
    for (int ii = 0; ii < 4; ++ii)
#pragma unroll
        for (int u = 0; u < 12; ++u) acc[ii][u] = 0.f;

    for (int k = 0; k < 256; ++k) {
        float qv[4];
#pragma unroll
        for (int ii = 0; ii < 4; ++ii) qv[ii] = smem[(tq * 4 + ii) * 256 + k];
        float wv[12];
#pragma unroll
        for (int u = 0; u < 12; ++u) {
            int j = tc + 32 * u;
            wv[u] = (u < 8) ? W_off[k * 256 + j] : W_attn[k * 128 + (j - 256)];
        }
#pragma unroll
        for (int ii = 0; ii < 4; ++ii)
#pragma unroll
            for (int u = 0; u < 12; ++u) acc[ii][u] += qv[ii] * wv[u];
    }
    __syncthreads();   // done with q tile; reuse smem as res[32][384]

#pragma unroll
    for (int u = 0; u < 12; ++u) {
        int j = tc + 32 * u;
        float b = (u < 8) ? b_off[j] : b_attn[j - 256];
#pragma unroll
        for (int ii = 0; ii < 4; ++ii)
            smem[(tq * 4 + ii) * 384 + j] = acc[ii][u] + b;
    }
    __syncthreads();

    // softmax + sampling locations: thread -> (query i = t>>3, head h = t&7)
    const int i = t >> 3;
    const int h = t & 7;
    const int gq = base + i;
    const float* r = &smem[i * 384];

    float lg[16];
    float m = -1e30f;
#pragma unroll
    for (int lp = 0; lp < 16; ++lp) {
        lg[lp] = r[256 + h * 16 + lp];
        m = fmaxf(m, lg[lp]);
    }
    float s = 0.f;
#pragma unroll
    for (int lp = 0; lp < 16; ++lp) { lg[lp] = __expf(lg[lp] - m); s += lg[lp]; }
    float inv = 1.0f / s;
#pragma unroll
    for (int lp = 0; lp < 16; ++lp) ws_attn[gq * 128 + h * 16 + lp] = lg[lp] * inv;

    const float Sf[4] = {100.f, 50.f, 25.f, 13.f};
    float2* out2 = (float2*)ws_loc;
#pragma unroll
    for (int l = 0; l < 4; ++l) {
        float rx = refp[(gq * 4 + l) * 2 + 0];
        float ry = refp[(gq * 4 + l) * 2 + 1];
#pragma unroll
        for (int p = 0; p < 4; ++p) {
            int lp = l * 4 + p;
            float ox = r[(h * 16 + lp) * 2 + 0];
            float oy = r[(h * 16 + lp) * 2 + 1];
            // loc = ref + off/S ; pixel = loc*S - 0.5  ==> ref*S + off - 0.5
            float px = rx * Sf[l] + ox - 0.5f;
            float py = ry * Sf[l] + oy - 0.5f;
            out2[gq * 128 + h * 16 + lp] = make_float2(px, py);
        }
    }
}

// ---------------------------------------------------------------------------
// Kernel B: bilinear gather + attention-weighted accumulate.
// One block per query, thread = output channel (h*32+d).
// ---------------------------------------------------------------------------
__global__ __launch_bounds__(256) void sample_kernel(
    const float* __restrict__ fm,
    const float* __restrict__ ws_loc,
    const float* __restrict__ ws_attn,
    float* __restrict__ mid)
{
    __shared__ float2 lloc[128];
    __shared__ float latt[128];
    const int gq = blockIdx.x;
    const int n = gq >> 12;
    const int t = threadIdx.x;
    if (t < 128) {
        lloc[t] = ((const float2*)ws_loc)[gq * 128 + t];
        latt[t] = ws_attn[gq * 128 + t];
    }
    __syncthreads();

    const int h = t >> 5;
    const float* fmc = fm + n * 256 + t;   // + pos*2048 indexes (pos, n, c)
    float acc = 0.f;

    const int starts[4] = {0, 10000, 12500, 13125};
    const int Ss[4] = {100, 50, 25, 13};

#pragma unroll
    for (int l = 0; l < 4; ++l) {
        const int Sl = Ss[l];
        const long lvlbase = (long)starts[l];
#pragma unroll
        for (int p = 0; p < 4; ++p) {
            int idx = h * 16 + l * 4 + p;
            float2 pc = lloc[idx];
            float a = latt[idx];
            float x0f = floorf(pc.x), y0f = floorf(pc.y);
            float wx = pc.x - x0f, wy = pc.y - y0f;
            int x0 = (int)x0f, y0 = (int)y0f;
            bool xv0 = (unsigned)x0 < (unsigned)Sl;
            bool xv1 = (unsigned)(x0 + 1) < (unsigned)Sl;
            bool yv0 = (unsigned)y0 < (unsigned)Sl;
            bool yv1 = (unsigned)(y0 + 1) < (unsigned)Sl;
            float v00 = 0.f, v01 = 0.f, v10 = 0.f, v11 = 0.f;
            long row0 = (lvlbase + (long)y0 * Sl + x0) * 2048;
            if (yv0) {
                if (xv0) v00 = fmc[row0];
                if (xv1) v01 = fmc[row0 + 2048];
            }
            if (yv1) {
                long row1 = row0 + (long)Sl * 2048;
                if (xv0) v10 = fmc[row1];
                if (xv1) v11 = fmc[row1 + 2048];
            }
            acc += a * ((1.f - wx) * (1.f - wy) * v00 + wx * (1.f - wy) * v01 +
                        (1.f - wx) * wy * v10 + wx * wy * v11);
        }
    }
    mid[(size_t)gq * 256 + t] = acc;
}

// ---------------------------------------------------------------------------
// Kernel C: mid @ W_out + b_out, transposed write to (Lq, N, C).
// ---------------------------------------------------------------------------
__global__ __launch_bounds__(256) void out_kernel(
    const float* __restrict__ mid,
    const float* __restrict__ W_out, const float* __restrict__ b_out,
    float* __restrict__ out)
{
    __shared__ float qs[32 * 256];
    const int t = threadIdx.x;
    const int base = blockIdx.x * 32;
    for (int idx = t; idx < 32 * 256; idx += 256)
        qs[idx] = mid[(size_t)base * 256 + idx];
    __syncthreads();

    const int tq = t >> 5, tc = t & 31;
    float acc[4][8];
#pragma unroll
    for (int ii = 0; ii < 4; ++ii)
#pragma unroll
        for (int u = 0; u < 8; ++u) acc[ii][u] = 0.f;

    for (int k = 0; k < 256; ++k) {
        float qv[4];
#pragma unroll
        for (int ii = 0; ii < 4; ++ii) qv[ii] = qs[(tq * 4 + ii) * 256 + k];
        float wv[8];
#pragma unroll
        for (int u = 0; u < 8; ++u) wv[u] = W_out[k * 256 + tc + 32 * u];
#pragma unroll
        for (int ii = 0; ii < 4; ++ii)
#pragma unroll
            for (int u = 0; u < 8; ++u) acc[ii][u] += qv[ii] * wv[u];
    }

#pragma unroll
    for (int u = 0; u < 8; ++u) {
        int j = tc + 32 * u;
        float b = b_out[j];
#pragma unroll
        for (int ii = 0; ii < 4; ++ii) {
            int gq = base + tq * 4 + ii;
            int n = gq >> 12, lq = gq & 4095;
            out[(size_t)(lq * 8 + n) * 256 + j] = acc[ii][u] + b;
        }
    }
}

extern "C" void kernel_launch(void* const* d_in, const int* in_sizes, int n_in,
                              void* d_out, int out_size, void* d_ws, size_t ws_size,
                              hipStream_t stream) {
    const float* query  = (const float*)d_in[0];
    const float* refp   = (const float*)d_in[1];
    const float* fm     = (const float*)d_in[2];
    // d_in[3] = spatial_shapes (constant, hardcoded)
    const float* W_off  = (const float*)d_in[4];
    const float* b_off  = (const float*)d_in[5];
    const float* W_attn = (const float*)d_in[6];
    const float* b_attn = (const float*)d_in[7];
    const float* W_out  = (const float*)d_in[8];
    const float* b_out  = (const float*)d_in[9];
    float* out = (float*)d_out;

    float* ws_loc  = (float*)d_ws;                         // NLQ*128*2 floats (33.5 MB)
    float* ws_attn = ws_loc + (size_t)NLQ * 128 * 2;       // NLQ*128   floats (16.7 MB)
    float* mid     = ws_attn + (size_t)NLQ * 128;          // NLQ*256   floats (33.5 MB)

    proj_kernel<<<NLQ / 32, 256, 0, stream>>>(query, refp, W_off, b_off,
                                              W_attn, b_attn, ws_loc, ws_attn);
    sample_kernel<<<NLQ, 256, 0, stream>>>(fm, ws_loc, ws_attn, mid);
    out_kernel<<<NLQ / 32, 256, 0, stream>>>(mid, W_out, b_out, out);
}

// Round 2
// 284.076 us; speedup vs baseline: 1.6095x; 1.6095x over previous
//
#include <hip/hip_runtime.h>

typedef unsigned short u16;
typedef __attribute__((ext_vector_type(8))) __bf16 bf16x8;
typedef __attribute__((ext_vector_type(4))) float f32x4;

#define NLQ 32768          // N*Lq
#define QN  (NLQ*256)      // query elements
#define WPN (384*256)      // proj weight elements
#define WON (256*256)      // out weight elements

static __device__ __forceinline__ u16 f2bf(float f) {
    unsigned u = __float_as_uint(f);
    return (u16)((u + 0x7fffu + ((u >> 16) & 1u)) >> 16);   // RNE
}

// ---------------------------------------------------------------------------
// Convert: query -> qbf[(n*4096+lq)*256+c] bf16 ; W_off|W_attn -> wtp[j][k] ;
// W_out -> wto[j][k] (both transposed so MFMA B-frags load contiguous k).
// ---------------------------------------------------------------------------
__global__ __launch_bounds__(256) void convert_kernel(
    const float* __restrict__ q,
    const float* __restrict__ W_off, const float* __restrict__ W_attn,
    const float* __restrict__ W_out,
    u16* __restrict__ qbf, u16* __restrict__ wtp, u16* __restrict__ wto)
{
    size_t i = (size_t)blockIdx.x * 256 + threadIdx.x;
    if (i < QN) {
        size_t gq = i >> 8, c = i & 255;
        size_t lq = gq & 4095, n = gq >> 12;
        qbf[i] = f2bf(q[(lq * 8 + n) * 256 + c]);
    } else if (i < QN + WPN) {
        size_t i2 = i - QN;
        int j = (int)(i2 >> 8), k = (int)(i2 & 255);
        float v = (j < 256) ? W_off[k * 256 + j] : W_attn[k * 128 + (j - 256)];
        wtp[i2] = f2bf(v);
    } else {
        size_t i3 = i - QN - WPN;
        int j = (int)(i3 >> 8), k = (int)(i3 & 255);
        wto[i3] = f2bf(W_out[k * 256 + j]);
    }
}

// ---------------------------------------------------------------------------
// MFMA GEMM: C(32768 x 384) = qbf(32768 x 256) * Wt^T ; raw proj + bias.
// Block 128x128, 4 waves (2x2), wave tile 64x64 = 4x4 frags of 16x16x32.
// ---------------------------------------------------------------------------
__global__ __launch_bounds__(256) void proj_gemm(
    const u16* __restrict__ A, const u16* __restrict__ Bt,
    const float* __restrict__ b_off, const float* __restrict__ b_attn,
    float* __restrict__ C)
{
    const int t = threadIdx.x;
    const int wid = t >> 6, lane = t & 63;
    const int lr = lane & 15, lk = lane >> 4;
    const int mrow = blockIdx.x * 128 + (wid >> 1) * 64;
    const int ncol = blockIdx.y * 128 + (wid & 1) * 64;
    const int kO = lk * 8;

    f32x4 acc[4][4] = {};
#pragma unroll
    for (int kk = 0; kk < 8; ++kk) {
        bf16x8 a[4], b[4];
#pragma unroll
        for (int mi = 0; mi < 4; ++mi)
            a[mi] = *(const bf16x8*)(A + (size_t)(mrow + mi * 16 + lr) * 256 + kk * 32 + kO);
#pragma unroll
        for (int ni = 0; ni < 4; ++ni)
            b[ni] = *(const bf16x8*)(Bt + (size_t)(ncol + ni * 16 + lr) * 256 + kk * 32 + kO);
#pragma unroll
        for (int mi = 0; mi < 4; ++mi)
#pragma unroll
            for (int ni = 0; ni < 4; ++ni)
                acc[mi][ni] = __builtin_amdgcn_mfma_f32_16x16x32_bf16(a[mi], b[ni], acc[mi][ni], 0, 0, 0);
    }

#pragma unroll
    for (int ni = 0; ni < 4; ++ni) {
        int gcol = ncol + ni * 16 + lr;
        float bias = (gcol < 256) ? b_off[gcol] : b_attn[gcol - 256];
#pragma unroll
        for (int mi = 0; mi < 4; ++mi) {
            f32x4 v = acc[mi][ni];
#pragma unroll
            for (int r = 0; r < 4; ++r)
                C[(size_t)(mrow + mi * 16 + lk * 4 + r) * 384 + gcol] = v[r] + bias;
        }
    }
}

// ---------------------------------------------------------------------------
// Fused softmax + loc + bilinear gather. One block per query.
// ---------------------------------------------------------------------------
__global__ __launch_bounds__(256) void sample_kernel(
    const float* __restrict__ fm,
    const float* __restrict__ proj,
    const float* __restrict__ refp,
    u16* __restrict__ mid)
{
    __shared__ float2 lloc[128];
    __shared__ float latt[128];
    const int gq = blockIdx.x;
    const int n = gq >> 12;
    const int t = threadIdx.x;

    if (t < 128) {
        // softmax over the 16 logits of head h = t>>4 (16-lane groups)
        float lg = proj[(size_t)gq * 384 + 256 + t];
        float m = lg;
#pragma unroll
        for (int msk = 1; msk < 16; msk <<= 1) m = fmaxf(m, __shfl_xor(m, msk));
        float e = __expf(lg - m);
        float s = e;
#pragma unroll
        for (int msk = 1; msk < 16; msk <<= 1) s += __shfl_xor(s, msk);
        latt[t] = e / s;
        // sampling location (pixel coords): ref*S + off - 0.5
        float ox = proj[(size_t)gq * 384 + 2 * t];
        float oy = proj[(size_t)gq * 384 + 2 * t + 1];
        int lp = t & 15, l = lp >> 2;
        float Sf = (l == 0) ? 100.f : (l == 1) ? 50.f : (l == 2) ? 25.f : 13.f;
        float rx = refp[((size_t)gq * 4 + l) * 2 + 0];
        float ry = refp[((size_t)gq * 4 + l) * 2 + 1];
        lloc[t] = make_float2(rx * Sf + ox - 0.5f, ry * Sf + oy - 0.5f);
    }
    __syncthreads();

    const int h = t >> 5;
    const float* fmc = fm + n * 256 + t;   // + pos*2048 indexes (pos, n, c)
    float acc = 0.f;

    const int starts[4] = {0, 10000, 12500, 13125};
    const int Ss[4] = {100, 50, 25, 13};

#pragma unroll
    for (int l = 0; l < 4; ++l) {
        const int Sl = Ss[l];
        const long lvlbase = (long)starts[l];
#pragma unroll
        for (int p = 0; p < 4; ++p) {
            int idx = h * 16 + l * 4 + p;
            float2 pc = lloc[idx];
            float a = latt[idx];
            float x0f = floorf(pc.x), y0f = floorf(pc.y);
            float wx = pc.x - x0f, wy = pc.y - y0f;
            int x0 = (int)x0f, y0 = (int)y0f;
            bool xv0 = (unsigned)x0 < (unsigned)Sl;
            bool xv1 = (unsigned)(x0 + 1) < (unsigned)Sl;
            bool yv0 = (unsigned)y0 < (unsigned)Sl;
            bool yv1 = (unsigned)(y0 + 1) < (unsigned)Sl;
            float v00 = 0.f, v01 = 0.f, v10 = 0.f, v11 = 0.f;
            long row0 = (lvlbase + (long)y0 * Sl + x0) * 2048;
            if (yv0) {
                if (xv0) v00 = fmc[row0];
                if (xv1) v01 = fmc[row0 + 2048];
            }
            if (yv1) {
                long row1 = row0 + (long)Sl * 2048;
                if (xv0) v10 = fmc[row1];
                if (xv1) v11 = fmc[row1 + 2048];
            }
            acc += a * ((1.f - wx) * (1.f - wy) * v00 + wx * (1.f - wy) * v01 +
                        (1.f - wx) * wy * v10 + wx * wy * v11);
        }
    }
    mid[(size_t)gq * 256 + t] = f2bf(acc);
}

// ---------------------------------------------------------------------------
// MFMA GEMM: out = mid(32768 x 256, bf16) * W_out^T + b_out, transposed write.
// ---------------------------------------------------------------------------
__global__ __launch_bounds__(256) void out_gemm(
    const u16* __restrict__ A, const u16* __restrict__ Bt,
    const float* __restrict__ b_out,
    float* __restrict__ out)
{
    const int t = threadIdx.x;
    const int wid = t >> 6, lane = t & 63;
    const int lr = lane & 15, lk = lane >> 4;
    const int mrow = blockIdx.x * 128 + (wid >> 1) * 64;
    const int ncol = blockIdx.y * 128 + (wid & 1) * 64;
    const int kO = lk * 8;

    f32x4 acc[4][4] = {};
#pragma unroll
    for (int kk = 0; kk < 8; ++kk) {
        bf16x8 a[4], b[4];
#pragma unroll
        for (int mi = 0; mi < 4; ++mi)
            a[mi] = *(const bf16x8*)(A + (size_t)(mrow + mi * 16 + lr) * 256 + kk * 32 + kO);
#pragma unroll
        for (int ni = 0; ni < 4; ++ni)
            b[ni] = *(const bf16x8*)(Bt + (size_t)(ncol + ni * 16 + lr) * 256 + kk * 32 + kO);
#pragma unroll
        for (int mi = 0; mi < 4; ++mi)
#pragma unroll
            for (int ni = 0; ni < 4; ++ni)
                acc[mi][ni] = __builtin_amdgcn_mfma_f32_16x16x32_bf16(a[mi], b[ni], acc[mi][ni], 0, 0, 0);
    }

#pragma unroll
    for (int ni = 0; ni < 4; ++ni) {
        int gcol = ncol + ni * 16 + lr;
        float bias = b_out[gcol];
#pragma unroll
        for (int mi = 0; mi < 4; ++mi) {
            f32x4 v = acc[mi][ni];
#pragma unroll
            for (int r = 0; r < 4; ++r) {
                int grow = mrow + mi * 16 + lk * 4 + r;
                int nn = grow >> 12, lq = grow & 4095;
                out[(size_t)(lq * 8 + nn) * 256 + gcol] = v[r] + bias;
            }
        }
    }
}

extern "C" void kernel_launch(void* const* d_in, const int* in_sizes, int n_in,
                              void* d_out, int out_size, void* d_ws, size_t ws_size,
                              hipStream_t stream) {
    const float* query  = (const float*)d_in[0];
    const float* refp   = (const float*)d_in[1];
    const float* fm     = (const float*)d_in[2];
    const float* W_off  = (const float*)d_in[4];
    const float* b_off  = (const float*)d_in[5];
    const float* W_attn = (const float*)d_in[6];
    const float* b_attn = (const float*)d_in[7];
    const float* W_out  = (const float*)d_in[8];
    const float* b_out  = (const float*)d_in[9];
    float* out = (float*)d_out;

    // workspace layout
    float* ws_proj = (float*)d_ws;                       // 32768*384 f32 (50.3 MB)
    u16*   qbf     = (u16*)(ws_proj + (size_t)NLQ * 384);// 32768*256 bf16 (16.8 MB)
    u16*   wtp     = qbf + (size_t)NLQ * 256;            // 384*256 bf16
    u16*   wto     = wtp + (size_t)WPN;                  // 256*256 bf16
    u16*   mid     = wto + (size_t)WON;                  // 32768*256 bf16 (16.8 MB)

    const int TOT = QN + WPN + WON;                      // 8552448 = 33408*256
    convert_kernel<<<TOT / 256, 256, 0, stream>>>(query, W_off, W_attn, W_out,
                                                  qbf, wtp, wto);
    proj_gemm<<<dim3(256, 3), 256, 0, stream>>>(qbf, wtp, b_off, b_attn, ws_proj);
    sample_kernel<<<NLQ, 256, 0, stream>>>(fm, ws_proj, refp, mid);
    out_gemm<<<dim3(256, 2), 256, 0, stream>>>(mid, wto, b_out, out);
}

// Round 3
// 145.976 us; speedup vs baseline: 3.1322x; 1.9460x over previous
//
#include <hip/hip_runtime.h>

typedef unsigned short u16;
typedef __attribute__((ext_vector_type(8))) __bf16 bf16x8;
typedef __attribute__((ext_vector_type(4))) float f32x4;
typedef __attribute__((ext_vector_type(4))) int   i32x4;

#define NLQ 32768          // N*Lq
#define QN  (NLQ*256)      // query elements
#define WPN (384*256)      // proj weight elements
#define WON (256*256)      // out weight elements

static __device__ __forceinline__ u16 f2bf(float f) {
    unsigned u = __float_as_uint(f);
    return (u16)((u + 0x7fffu + ((u >> 16) & 1u)) >> 16);   // RNE
}

// ---------------------------------------------------------------------------
// Convert: query -> qbf[(n*4096+lq)*256+c] bf16 ; W_off|W_attn -> wtp[j][k] ;
// W_out -> wto[j][k] (both transposed so MFMA B-frags load contiguous k).
// ---------------------------------------------------------------------------
__global__ __launch_bounds__(256) void convert_kernel(
    const float* __restrict__ q,
    const float* __restrict__ W_off, const float* __restrict__ W_attn,
    const float* __restrict__ W_out,
    u16* __restrict__ qbf, u16* __restrict__ wtp, u16* __restrict__ wto)
{
    size_t i = (size_t)blockIdx.x * 256 + threadIdx.x;
    if (i < QN) {
        size_t gq = i >> 8, c = i & 255;
        size_t lq = gq & 4095, n = gq >> 12;
        qbf[i] = f2bf(q[(lq * 8 + n) * 256 + c]);
    } else if (i < QN + WPN) {
        size_t i2 = i - QN;
        int j = (int)(i2 >> 8), k = (int)(i2 & 255);
        float v = (j < 256) ? W_off[k * 256 + j] : W_attn[k * 128 + (j - 256)];
        wtp[i2] = f2bf(v);
    } else {
        size_t i3 = i - QN - WPN;
        int j = (int)(i3 >> 8), k = (int)(i3 & 255);
        wto[i3] = f2bf(W_out[k * 256 + j]);
    }
}

// ---------------------------------------------------------------------------
// MFMA GEMM: C(32768 x 384) = qbf(32768 x 256) * Wt^T ; raw proj + bias.
// ---------------------------------------------------------------------------
__global__ __launch_bounds__(256) void proj_gemm(
    const u16* __restrict__ A, const u16* __restrict__ Bt,
    const float* __restrict__ b_off, const float* __restrict__ b_attn,
    float* __restrict__ C)
{
    const int t = threadIdx.x;
    const int wid = t >> 6, lane = t & 63;
    const int lr = lane & 15, lk = lane >> 4;
    const int mrow = blockIdx.x * 128 + (wid >> 1) * 64;
    const int ncol = blockIdx.y * 128 + (wid & 1) * 64;
    const int kO = lk * 8;

    f32x4 acc[4][4] = {};
#pragma unroll
    for (int kk = 0; kk < 8; ++kk) {
        bf16x8 a[4], b[4];
#pragma unroll
        for (int mi = 0; mi < 4; ++mi)
            a[mi] = *(const bf16x8*)(A + (size_t)(mrow + mi * 16 + lr) * 256 + kk * 32 + kO);
#pragma unroll
        for (int ni = 0; ni < 4; ++ni)
            b[ni] = *(const bf16x8*)(Bt + (size_t)(ncol + ni * 16 + lr) * 256 + kk * 32 + kO);
#pragma unroll
        for (int mi = 0; mi < 4; ++mi)
#pragma unroll
            for (int ni = 0; ni < 4; ++ni)
                acc[mi][ni] = __builtin_amdgcn_mfma_f32_16x16x32_bf16(a[mi], b[ni], acc[mi][ni], 0, 0, 0);
    }

#pragma unroll
    for (int ni = 0; ni < 4; ++ni) {
        int gcol = ncol + ni * 16 + lr;
        float bias = (gcol < 256) ? b_off[gcol] : b_attn[gcol - 256];
#pragma unroll
        for (int mi = 0; mi < 4; ++mi) {
            f32x4 v = acc[mi][ni];
#pragma unroll
            for (int r = 0; r < 4; ++r)
                C[(size_t)(mrow + mi * 16 + lk * 4 + r) * 384 + gcol] = v[r] + bias;
        }
    }
}

// ---------------------------------------------------------------------------
// Fused softmax + loc + bilinear gather. One block per query.
// Prologue (t<128): softmax, sampling locations, clamped corner offsets
// (float4 units) + validity-and-attention-premultiplied weights into LDS.
// Main: head h = t>>5; 8 lanes x float4 per corner; 4 points per lane-group.
// ---------------------------------------------------------------------------
__global__ __launch_bounds__(256) void sample_kernel(
    const float* __restrict__ fm,
    const float* __restrict__ proj,
    const float* __restrict__ refp,
    u16* __restrict__ mid)
{
    __shared__ i32x4 loff[128];
    __shared__ f32x4 lwv[128];
    const int gq = blockIdx.x;
    const int n = gq >> 12;
    const int t = threadIdx.x;

    if (t < 128) {
        const int lp = t & 15, l = lp >> 2;
        // softmax over the 16 logits of head h = t>>4
        float lg = proj[(size_t)gq * 384 + 256 + t];
        float m = lg;
#pragma unroll
        for (int msk = 1; msk < 16; msk <<= 1) m = fmaxf(m, __shfl_xor(m, msk));
        float e = __expf(lg - m);
        float s = e;
#pragma unroll
        for (int msk = 1; msk < 16; msk <<= 1) s += __shfl_xor(s, msk);
        float a = e / s;

        float ox = proj[(size_t)gq * 384 + 2 * t];
        float oy = proj[(size_t)gq * 384 + 2 * t + 1];
        int   Sl = (l == 0) ? 100 : (l == 1) ? 50 : (l == 2) ? 25 : 13;
        int   lb = (l == 0) ? 0 : (l == 1) ? 10000 : (l == 2) ? 12500 : 13125;
        float Sf = (float)Sl;
        float rx = refp[((size_t)gq * 4 + l) * 2 + 0];
        float ry = refp[((size_t)gq * 4 + l) * 2 + 1];
        float px = rx * Sf + ox - 0.5f;
        float py = ry * Sf + oy - 0.5f;
        float x0f = floorf(px), y0f = floorf(py);
        float wx = px - x0f, wy = py - y0f;
        int x0 = (int)x0f, y0 = (int)y0f;
        bool xv0 = (unsigned)x0 < (unsigned)Sl;
        bool xv1 = (unsigned)(x0 + 1) < (unsigned)Sl;
        bool yv0 = (unsigned)y0 < (unsigned)Sl;
        bool yv1 = (unsigned)(y0 + 1) < (unsigned)Sl;
        int x0c = min(max(x0, 0), Sl - 1), x1c = min(max(x0 + 1, 0), Sl - 1);
        int y0c = min(max(y0, 0), Sl - 1), y1c = min(max(y0 + 1, 0), Sl - 1);
        int r0 = (lb + y0c * Sl) * 512, r1 = (lb + y1c * Sl) * 512;
        i32x4 o; f32x4 w;
        o.x = r0 + x0c * 512; o.y = r0 + x1c * 512;
        o.z = r1 + x0c * 512; o.w = r1 + x1c * 512;
        w.x = (xv0 && yv0) ? a * (1.f - wx) * (1.f - wy) : 0.f;
        w.y = (xv1 && yv0) ? a * wx * (1.f - wy) : 0.f;
        w.z = (xv0 && yv1) ? a * (1.f - wx) * wy : 0.f;
        w.w = (xv1 && yv1) ? a * wx * wy : 0.f;
        loff[t] = o;
        lwv[t] = w;
    }
    __syncthreads();

    const int h = t >> 5, ll = t & 31, g = ll >> 3, cq = ll & 7;
    const f32x4* __restrict__ fmc = (const f32x4*)fm + (size_t)n * 64 + h * 8 + cq;
    f32x4 acc = {0.f, 0.f, 0.f, 0.f};
#pragma unroll
    for (int pi = 0; pi < 4; ++pi) {
        int idx = h * 16 + pi * 4 + g;
        i32x4 o = loff[idx];
        f32x4 w = lwv[idx];
        f32x4 v0 = fmc[o.x];
        f32x4 v1 = fmc[o.y];
        f32x4 v2 = fmc[o.z];
        f32x4 v3 = fmc[o.w];
        acc += w.x * v0 + w.y * v1 + w.z * v2 + w.w * v3;
    }
    // reduce across the 4 point-groups (lane bits 3 and 4)
    f32x4 tmp;
    tmp.x = __shfl_xor(acc.x, 8); tmp.y = __shfl_xor(acc.y, 8);
    tmp.z = __shfl_xor(acc.z, 8); tmp.w = __shfl_xor(acc.w, 8);
    acc += tmp;
    tmp.x = __shfl_xor(acc.x, 16); tmp.y = __shfl_xor(acc.y, 16);
    tmp.z = __shfl_xor(acc.z, 16); tmp.w = __shfl_xor(acc.w, 16);
    acc += tmp;

    if (ll < 8) {
        ushort4 r;
        r.x = f2bf(acc.x); r.y = f2bf(acc.y);
        r.z = f2bf(acc.z); r.w = f2bf(acc.w);
        ((ushort4*)mid)[(size_t)gq * 64 + h * 8 + cq] = r;
    }
}

// ---------------------------------------------------------------------------
// MFMA GEMM: out = mid(32768 x 256, bf16) * W_out^T + b_out, transposed write.
// ---------------------------------------------------------------------------
__global__ __launch_bounds__(256) void out_gemm(
    const u16* __restrict__ A, const u16* __restrict__ Bt,
    const float* __restrict__ b_out,
    float* __restrict__ out)
{
    const int t = threadIdx.x;
    const int wid = t >> 6, lane = t & 63;
    const int lr = lane & 15, lk = lane >> 4;
    const int mrow = blockIdx.x * 128 + (wid >> 1) * 64;
    const int ncol = blockIdx.y * 128 + (wid & 1) * 64;
    const int kO = lk * 8;

    f32x4 acc[4][4] = {};
#pragma unroll
    for (int kk = 0; kk < 8; ++kk) {
        bf16x8 a[4], b[4];
#pragma unroll
        for (int mi = 0; mi < 4; ++mi)
            a[mi] = *(const bf16x8*)(A + (size_t)(mrow + mi * 16 + lr) * 256 + kk * 32 + kO);
#pragma unroll
        for (int ni = 0; ni < 4; ++ni)
            b[ni] = *(const bf16x8*)(Bt + (size_t)(ncol + ni * 16 + lr) * 256 + kk * 32 + kO);
#pragma unroll
        for (int mi = 0; mi < 4; ++mi)
#pragma unroll
            for (int ni = 0; ni < 4; ++ni)
                acc[mi][ni] = __builtin_amdgcn_mfma_f32_16x16x32_bf16(a[mi], b[ni], acc[mi][ni], 0, 0, 0);
    }

#pragma unroll
    for (int ni = 0; ni < 4; ++ni) {
        int gcol = ncol + ni * 16 + lr;
        float bias = b_out[gcol];
#pragma unroll
        for (int mi = 0; mi < 4; ++mi) {
            f32x4 v = acc[mi][ni];
#pragma unroll
            for (int r = 0; r < 4; ++r) {
                int grow = mrow + mi * 16 + lk * 4 + r;
                int nn = grow >> 12, lq = grow & 4095;
                out[(size_t)(lq * 8 + nn) * 256 + gcol] = v[r] + bias;
            }
        }
    }
}

extern "C" void kernel_launch(void* const* d_in, const int* in_sizes, int n_in,
                              void* d_out, int out_size, void* d_ws, size_t ws_size,
                              hipStream_t stream) {
    const float* query  = (const float*)d_in[0];
    const float* refp   = (const float*)d_in[1];
    const float* fm     = (const float*)d_in[2];
    const float* W_off  = (const float*)d_in[4];
    const float* b_off  = (const float*)d_in[5];
    const float* W_attn = (const float*)d_in[6];
    const float* b_attn = (const float*)d_in[7];
    const float* W_out  = (const float*)d_in[8];
    const float* b_out  = (const float*)d_in[9];
    float* out = (float*)d_out;

    // workspace layout
    float* ws_proj = (float*)d_ws;                       // 32768*384 f32 (50.3 MB)
    u16*   qbf     = (u16*)(ws_proj + (size_t)NLQ * 384);// 32768*256 bf16 (16.8 MB)
    u16*   wtp     = qbf + (size_t)NLQ * 256;            // 384*256 bf16
    u16*   wto     = wtp + (size_t)WPN;                  // 256*256 bf16
    u16*   mid     = wto + (size_t)WON;                  // 32768*256 bf16 (16.8 MB)

    const int TOT = QN + WPN + WON;                      // 8552448 = 33408*256
    convert_kernel<<<TOT / 256, 256, 0, stream>>>(query, W_off, W_attn, W_out,
                                                  qbf, wtp, wto);
    proj_gemm<<<dim3(256, 3), 256, 0, stream>>>(qbf, wtp, b_off, b_attn, ws_proj);
    sample_kernel<<<NLQ, 256, 0, stream>>>(fm, ws_proj, refp, mid);
    out_gemm<<<dim3(256, 2), 256, 0, stream>>>(mid, wto, b_out, out);
}